// Round 9
// baseline (942.584 us; speedup 1.0000x reference)
//
#include <hip/hip_runtime.h>
#include <hip/hip_fp16.h>
#include <stdint.h>

static constexpr int CI = 16;
static constexpr int CO = 32;
static constexpr int H  = 300000;
static constexpr int K  = 27;
static constexpr float BN_EPS = 1e-5f;

// ---------- f16 helpers ----------
typedef _Float16 h2_t __attribute__((ext_vector_type(2)));

__device__ __forceinline__ unsigned int pack_f16(float lo, float hi) {
    union { h2_t h; unsigned int u; } v;
    v.h[0] = (_Float16)lo;
    v.h[1] = (_Float16)hi;
    return v.u;
}

// acc += a.lo*b.lo + a.hi*b.hi  (v_dot2_f32_f16)
__device__ __forceinline__ float dot2f(unsigned int a, unsigned int b, float c) {
#if __has_builtin(__builtin_amdgcn_fdot2)
    union { unsigned int u; h2_t h; } ua, ub;
    ua.u = a; ub.u = b;
    return __builtin_amdgcn_fdot2(ua.h, ub.h, c, false);
#else
    union { unsigned int u; h2_t h; } ua, ub;
    ua.u = a; ub.u = b;
    float r = fmaf((float)ua.h[0], (float)ub.h[0], c);
    return fmaf((float)ua.h[1], (float)ub.h[1], r);
#endif
}

// async row gather: issues two global_load_dwordx4 into (a,b), NO wait.
// asm volatile + early-clobber outputs keep it pinned and non-collapsible
// (the R4/R6 C++ failure mode). No "memory" clobber: volatile asm is already
// ordered w.r.t. other volatile asm, and the waits carry the fence.
__device__ __forceinline__ void issue_row(uint4& a, uint4& b,
                                          const unsigned int* __restrict__ xTp,
                                          int idx) {
    uint64_t addr = (uint64_t)(xTp + (size_t)(idx < 0 ? 0 : idx) * 8);
    asm volatile("global_load_dwordx4 %0, %2, off\n\t"
                 "global_load_dwordx4 %1, %2, off offset:16"
                 : "=&v"(a), "=&v"(b)
                 : "v"(addr));
}

template<int N>
__device__ __forceinline__ void wait_vmcnt() {
    static_assert(N == 0 || N == 2 || N == 4, "unexpected vmcnt");
    if constexpr (N == 4)      asm volatile("s_waitcnt vmcnt(4)" ::: "memory");
    else if constexpr (N == 2) asm volatile("s_waitcnt vmcnt(2)" ::: "memory");
    else                       asm volatile("s_waitcnt vmcnt(0)" ::: "memory");
    __builtin_amdgcn_sched_barrier(0);      // rule #18: pin consumers below the wait
}

// ---------- kernel 1: fused prep ----------
// x fp32 (CI,H) -> xTp f16-pair rows (H x 8 dwords, 32 B/row);
// w fp32 (o,i,k) -> wp[(k*32+o)*8+j] = (w[o,2j,k], w[o,2j+1,k]) f16 pairs;
// zero stats[64].
__global__ __launch_bounds__(256) void prep(const float* __restrict__ x,
                                            const float* __restrict__ w,
                                            unsigned int* __restrict__ xTp,
                                            unsigned int* __restrict__ wp,
                                            float* __restrict__ stats) {
    int h = blockIdx.x * 256 + threadIdx.x;
    if (h < H) {
        unsigned int r[8];
        #pragma unroll
        for (int j = 0; j < 8; ++j)
            r[j] = pack_f16(x[(size_t)(2 * j) * H + h], x[(size_t)(2 * j + 1) * H + h]);
        uint4* dst = reinterpret_cast<uint4*>(xTp + (size_t)h * 8);
        dst[0] = make_uint4(r[0], r[1], r[2], r[3]);
        dst[1] = make_uint4(r[4], r[5], r[6], r[7]);
    }
    if (blockIdx.x == 0) {
        for (int idx = threadIdx.x; idx < K * CO * 8; idx += 256) {
            int j = idx & 7;
            int o = (idx >> 3) & 31;
            int k = idx >> 8;
            float lo = w[((size_t)o * CI + 2 * j) * K + k];
            float hi = w[((size_t)o * CI + 2 * j + 1) * K + k];
            wp[idx] = pack_f16(lo, hi);
        }
        if (threadIdx.x < 64) stats[threadIdx.x] = 0.f;   // gsum[32] ++ gsq[32]
    }
}

// one pipeline step (fully unrolled at the call sites — k_ is compile-time
// after unroll, so np[] reads are immediate-offset ds_read and weight reads
// are immediate-offset s_load). ISSUE: issue row k_+2 into (anx,bnx,inx).
// Then wait for row k_'s loads (VMCNT = 2x rows still in flight) and consume
// row k_ from (acur,bcur,icur).
template<int VMCNT, bool ISSUE>
__device__ __forceinline__ void conv_step(int k_, const int* np,
                                          const unsigned int* __restrict__ xTp,
                                          const unsigned int* __restrict__ wh,
                                          float (&acc)[16],
                                          uint4& acur, uint4& bcur, int icur,
                                          uint4& anx,  uint4& bnx,  int& inx) {
    if constexpr (ISSUE) {
        inx = np[k_ + 2];
        issue_row(anx, bnx, xTp, inx);
    }
    wait_vmcnt<VMCNT>();

    uint4 a = acur, b = bcur;
    if (icur < 0) {                         // cndmask zero for invalid neighbor
        a.x = a.y = a.z = a.w = 0u;
        b.x = b.y = b.z = b.w = 0u;
    }
    const unsigned int* wk = wh + k_ * 256; // wave-uniform -> scalar loads
    #pragma unroll
    for (int o = 0; o < 16; ++o) {
        float s = acc[o];
        s = dot2f(a.x, wk[o * 8 + 0], s);
        s = dot2f(a.y, wk[o * 8 + 1], s);
        s = dot2f(a.z, wk[o * 8 + 2], s);
        s = dot2f(a.w, wk[o * 8 + 3], s);
        s = dot2f(b.x, wk[o * 8 + 4], s);
        s = dot2f(b.y, wk[o * 8 + 5], s);
        s = dot2f(b.z, wk[o * 8 + 6], s);
        s = dot2f(b.w, wk[o * 8 + 7], s);
        acc[o] = s;
    }
}

// ---------- kernel 2: gathered conv (f16 dot2) + fused BN stats ----------
// R0 structure (2 threads/h split by output halves, acc[16], LDS-staged
// neigh, 9376 waves) + inline-asm DEPTH-2 gather pipeline: 2 rows (4
// dwordx4) in flight during every compute phase. The k-loop is FULLY
// UNROLLED: no backedge phis, so the compiler cannot insert copies of
// registers whose loads are still in flight (suspected R8 abort cause).
// vmcnt ladder: steps 0..24 issue k+2 & wait vmcnt(4); 25: vmcnt(2);
// 26: vmcnt(0). Zero loads outstanding after the last step — no drain.
__global__ __launch_bounds__(256) void conv(const unsigned int* __restrict__ xTp,
                                            const unsigned int* __restrict__ wp,
                                            const int* __restrict__ neigh,
                                            float* __restrict__ out,
                                            float* __restrict__ stats) {
    __shared__ int snb[128 * K];
    const int t    = threadIdx.x;
    const int hl   = t & 127;
    const int half = __builtin_amdgcn_readfirstlane(t >> 7);   // wave-uniform 0/1
    const int h    = blockIdx.x * 128 + hl;

    // stage this block's neighbor indices coalesced into LDS (nontemporal stream)
    {
        const int base = blockIdx.x * 128 * K;
        #pragma unroll 1
        for (int s = t; s < 128 * K; s += 256) {
            int g = base + s;
            snb[s] = (g < H * K) ? __builtin_nontemporal_load(&neigh[g]) : -1;
        }
    }
    __syncthreads();

    float acc[16];
    #pragma unroll
    for (int o = 0; o < 16; ++o) acc[o] = 0.f;

    if (h < H) {
        const int* np = &snb[hl * K];
        const unsigned int* wh = wp + half * 128;   // this half's 16 outputs x 8 pairs

        // three rotating row-register sets, 2 rows in flight in steady state
        uint4 a0, b0, a1, b1, a2, b2;
        int i0, i1, i2;

        // prologue: rows 0 and 1 in flight (4 outstanding loads)
        i0 = np[0];
        issue_row(a0, b0, xTp, i0);
        i1 = np[1];
        issue_row(a1, b1, xTp, i1);

        #pragma unroll
        for (int j = 0; j < 8; ++j) {              // k = 0..23, FULLY UNROLLED
            const int k = 3 * j;
            conv_step<4, true>(k,     np, xTp, wh, acc, a0, b0, i0, a2, b2, i2);
            conv_step<4, true>(k + 1, np, xTp, wh, acc, a1, b1, i1, a0, b0, i0);
            conv_step<4, true>(k + 2, np, xTp, wh, acc, a2, b2, i2, a1, b1, i1);
        }
        // epilogue: k = 24 (last issue: row 26), 25, 26 — vmcnt 4 -> 2 -> 0
        conv_step<4, true >(24, np, xTp, wh, acc, a0, b0, i0, a2, b2, i2);
        conv_step<2, false>(25, np, xTp, wh, acc, a1, b1, i1, a0, b0, i0);
        conv_step<0, false>(26, np, xTp, wh, acc, a2, b2, i2, a1, b1, i1);

        #pragma unroll
        for (int o = 0; o < 16; ++o)
            out[(size_t)(half * 16 + o) * H + h] = acc[o];   // coalesced over h
    }

    // fused BN statistics: butterfly per output, one atomic per wave per output
    const unsigned lane = t & 63u;
    float mySum = 0.f, mySq = 0.f;
    #pragma unroll
    for (int o = 0; o < 16; ++o) {
        float v = acc[o];
        float q = v * v;
        #pragma unroll
        for (int d = 32; d > 0; d >>= 1) {
            v += __shfl_xor(v, d, 64);
            q += __shfl_xor(q, d, 64);
        }
        if (lane == (unsigned)o) { mySum = v; mySq = q; }
    }
    if (lane < 16u) {
        atomicAdd(&stats[half * 16 + lane], mySum);        // gsum
        atomicAdd(&stats[32 + half * 16 + lane], mySq);    // gsq
    }
}

// ---------- kernel 3: BN apply (scale/shift recomputed per thread from stats) ----------
__global__ __launch_bounds__(256) void bn_apply(float* __restrict__ out,
                                                const float* __restrict__ stats,
                                                const float* __restrict__ gamma,
                                                const float* __restrict__ beta) {
    size_t t = (size_t)blockIdx.x * 256 + threadIdx.x;
    size_t base = t * 4;
    if (base >= (size_t)CO * H) return;
    int o = (int)(base / (size_t)H);     // H % 4 == 0 -> float4 never crosses channels
    const float invH = 1.f / (float)H;
    float m   = stats[o] * invH;
    float var = stats[32 + o] * invH - m * m;
    float inv = rsqrtf(var + BN_EPS);
    float sc  = gamma[o] * inv;
    float sh  = beta[o] - m * sc;
    float4* p = reinterpret_cast<float4*>(out + base);
    float4 q = *p;
    q.x = q.x * sc + sh;
    q.y = q.y * sc + sh;
    q.z = q.z * sc + sh;
    q.w = q.w * sc + sh;
    *p = q;
}

// ---------- launch ----------
extern "C" void kernel_launch(void* const* d_in, const int* in_sizes, int n_in,
                              void* d_out, int out_size, void* d_ws, size_t ws_size,
                              hipStream_t stream) {
    const float* x     = (const float*)d_in[0];   // fp32 (1,CI,H,1)
    const float* w     = (const float*)d_in[1];   // fp32 (CO,CI,K)
    const float* gamma = (const float*)d_in[2];   // fp32 (CO)
    const float* beta  = (const float*)d_in[3];   // fp32 (CO)
    const int*   neigh = (const int*)d_in[4];     // int32 (H,K)
    float*       out   = (float*)d_out;           // fp32 (CO,H)

    char* ws = (char*)d_ws;
    const size_t XT_OFF    = 0;                    // H*8*4   = 9,600,000 B
    const size_t WP_OFF    = 9600000;              // 6912*4  = 27,648 B
    const size_t STATS_OFF = 9627648;              // 64 floats
    unsigned int* xTp   = (unsigned int*)(ws + XT_OFF);
    unsigned int* wp    = (unsigned int*)(ws + WP_OFF);
    float*        stats = (float*)(ws + STATS_OFF);

    const int HBP = (H + 255) / 256;               // 1172 (prep)
    prep<<<HBP, 256, 0, stream>>>(x, w, xTp, wp, stats);

    const int HBC = (H + 127) / 128;               // 2344 (conv: 128 h/block, asm depth-2)
    conv<<<HBC, 256, 0, stream>>>(xTp, wp, neigh, out, stats);

    const int NBN = (CO * H / 4 + 255) / 256;      // 9375
    bn_apply<<<NBN, 256, 0, stream>>>(out, stats, gamma, beta);
}